// Round 10
// baseline (1875.180 us; speedup 1.0000x reference)
//
#include <hip/hip_runtime.h>

// LSTMDecoder: B=1024, L=128, H=256, OUT=64, T=256, 2 layers.
// R20: R19 + in-order-vmcnt fix. R19's poll did `s_waitcnt vmcnt(0)` with
// 16 JUST-ISSUED weight loads outstanding (reissued at X end) -> since
// vmcnt retires in order, seeing the flag required draining ~128KB/CU
// (~2k cyc) every step on the critical path. R20: X ends with an EMPTY
// vm queue (tail waits 12/8/4/0, no trailing reissue); G does
// poll(clean) -> payload issue (2 loads) -> weight-chunk issue (16 loads)
// -> vmcnt(16) (retires only the 2 older payloads) -> scatter; weights
// stay in flight across bar1 into X. Plus flag PREFETCH: issue partner
// flag-quad load right after posting our flag at X end; G starts with
// vmcnt(0) on a 1-element queue -> first-poll RT usually free. w0's
// out-proj now runs on an empty queue too (R19 forced a weight drain).
// Everything else identical to R19: 64x4 partition (16 rows x 64 cols),
// 2-phase step {G,bar,X,bar}, per-wave flags, 2-slot boxes w/ transitive
// reuse proof, 8B coalesced pubs, 24-chunk/step weight streams, 3-deep
// h1 ring, bounded spin-guard.

typedef float f32x4 __attribute__((ext_vector_type(4)));
typedef short bf16x8 __attribute__((ext_vector_type(8)));
typedef unsigned short u16;
typedef unsigned int u32;
typedef unsigned int u32x2 __attribute__((ext_vector_type(2)));
typedef unsigned int u32x4 __attribute__((ext_vector_type(4)));

#define OFF_LH   0          // 32 tiles, KB=4
#define OFF_LC   65536      // 32 tiles, KB=4
#define OFF_IH0  131072     // 64 tiles, KB=4
#define OFF_HH0  262144     // 64 tiles, KB=8
#define OFF_IH1  524288     // 64 tiles, KB=8
#define OFF_HH1  786432     // 64 tiles, KB=8
#define OFF_OUT  1048576    // 4 tiles,  KB=8

// payload boxes: 2KB x 256 blocks x 2 kinds x 2 slots = 2MB
#define COMM_B   2228224
#define OBOX(bid,kind,slot) (COMM_B + ((((bid)*2+(kind))*2+(slot)) << 11))
// per-wave flag quads: 16B per (bid,kind)
#define FLAG_B   (COMM_B + 2097152)
#define FLAGQ(bid,kind) (FLAG_B + (((bid)*2+(kind)) << 4))
#define SPIN_LIMIT (1<<15)
#define HST 264

__device__ __forceinline__ u16 f2bf(float x){
  unsigned u = __builtin_bit_cast(unsigned, x);
  return (u16)((u + 0x7fffu + ((u >> 16) & 1u)) >> 16);  // RNE
}

__global__ __launch_bounds__(256) void convert_swizzle(
    const float* __restrict__ src, u16* __restrict__ dst,
    int ntiles, int kbshift)
{
  int idx = blockIdx.x * 256 + threadIdx.x;
  int kblocks = 1 << kbshift;
  int n = ntiles << (kbshift + 9);
  if (idx >= n) return;
  int j    = idx & 7;
  int lane = (idx >> 3) & 63;
  int t3   = idx >> 9;
  int kt   = t3 & (kblocks - 1);
  int nt   = t3 >> kbshift;
  int row  = nt * 16 + (lane & 15);
  int k    = kt * 32 + (lane >> 4) * 8 + j;
  dst[idx] = f2bf(src[row * (kblocks * 32) + k]);
}

__device__ __forceinline__ f32x4 mfma16(bf16x8 a, bf16x8 b, f32x4 c){
  return __builtin_amdgcn_mfma_f32_16x16x32_bf16(a, b, c, 0, 0, 0);
}
__device__ __forceinline__ bf16x8 ld8(const u16* p){ return *(const bf16x8*)p; }
__device__ __forceinline__ float sigm(float x){ return 1.f/(1.f + __expf(-x)); }
__device__ __forceinline__ float tanh_f(float x){ return 1.f - 2.f/(__expf(2.f*x) + 1.f); }

#define ISSUE4(Q, seg, kt) \
  asm volatile( \
    "global_load_dwordx4 %0, %4, %8\n\t" \
    "global_load_dwordx4 %1, %5, %8\n\t" \
    "global_load_dwordx4 %2, %6, %8\n\t" \
    "global_load_dwordx4 %3, %7, %8" \
    : "=&v"(Q[0]), "=&v"(Q[1]), "=&v"(Q[2]), "=&v"(Q[3]) \
    : "v"(voffW +           (u32)((kt)*1024)), \
      "v"(voffW + 131072u + (u32)((kt)*1024)), \
      "v"(voffW + 262144u + (u32)((kt)*1024)), \
      "v"(voffW + 393216u + (u32)((kt)*1024)), \
      "s"(seg) \
    : "memory")

#define WAITN(Q, lit) \
  asm volatile("s_waitcnt vmcnt(" lit ")" \
    : "+v"(Q[0]), "+v"(Q[1]), "+v"(Q[2]), "+v"(Q[3]) :: "memory")
#define WAITC(Q) WAITN(Q, "12")

#define MFMA4(afrag, Q) { \
  acc0 = mfma16(afrag, Q[0], acc0); \
  acc1 = mfma16(afrag, Q[1], acc1); \
  acc2 = mfma16(afrag, Q[2], acc2); \
  acc3 = mfma16(afrag, Q[3], acc3); }

#define BARX() asm volatile("s_waitcnt lgkmcnt(0)\n\ts_barrier" ::: "memory")
#define VDRAIN() asm volatile("s_waitcnt vmcnt(0)" ::: "memory")

__device__ __forceinline__ void stflag(u32* p, u32 v){
  __hip_atomic_store(p, v, __ATOMIC_RELAXED, __HIP_MEMORY_SCOPE_AGENT);
}
// coalesced 8B record: {rows hrow+0,+1 | rows hrow+2,+3} for one col
__device__ __forceinline__ void pub8(char* p, u32 lo, u32 hi){
  u32x2 v = {lo, hi};
  asm volatile("global_store_dwordx2 %0, %1, off sc0 sc1" :: "v"(p), "v"(v) : "memory");
}

// scatter one partner box's 32B/lane of col-records into full-h LDS
__device__ __forceinline__ void scat8(u16* hdst, u32x4 q0, u32x4 q1, int ps, int lane){
  const int r  = lane >> 4;            // producer wave region (hct4)
  const int cb = ps*64 + r*16;         // col base in full-h LDS
  #pragma unroll
  for (int j = 0; j < 4; ++j){
    u32 lo = (j < 2) ? q0[2*j]   : q1[2*(j-2)];
    u32 hi = (j < 2) ? q0[2*j+1] : q1[2*(j-2)+1];
    int pl = (lane & 15)*4 + j;        // producer lane within region
    u16* dst = &hdst[((pl >> 4)*4)*HST + cb + (pl & 15)];
    dst[0]     = (u16)lo;
    dst[HST]   = (u16)(lo >> 16);
    dst[2*HST] = (u16)hi;
    dst[3*HST] = (u16)(hi >> 16);
  }
}

// epilogue-only gather (clean queue at entry): poll + payload + scatter
__device__ __forceinline__ void gatherF1(u16* hdst,
    const char* pay, const char* fq, int ps, int lane, u32 tgt, int* dead)
{
  if (!*dead){
    int gc = 0;
    for(;;){
      u32x4 fa;
      asm volatile(
        "global_load_dwordx4 %0, %1, off sc0 sc1\n\ts_waitcnt vmcnt(0)"
        : "=&v"(fa) : "v"(fq) : "memory");
      if (fa[0] >= tgt && fa[1] >= tgt && fa[2] >= tgt && fa[3] >= tgt) break;
      if (++gc > SPIN_LIMIT){ *dead = 1; break; }
    }
  }
  u32x4 q0, q1;
  asm volatile(
    "global_load_dwordx4 %0, %2, off sc0 sc1\n\t"
    "global_load_dwordx4 %1, %3, off sc0 sc1"
    : "=&v"(q0), "=&v"(q1)
    : "v"(pay), "v"(pay+16)
    : "memory");
  asm volatile("s_waitcnt vmcnt(0)" : "+v"(q0), "+v"(q1) :: "memory");
  scat8(hdst, q0, q1, ps, lane);
}

__global__ __launch_bounds__(512)
void lstm_fused(
    const float* __restrict__ latent,
    const float* __restrict__ b_lh, const float* __restrict__ b_lc,
    const float* __restrict__ b_ih0, const float* __restrict__ b_hh0,
    const float* __restrict__ b_ih1, const float* __restrict__ b_hh1,
    const float* __restrict__ b_out,
    const u16* __restrict__ ws,
    u16* __restrict__ comm,
    float* __restrict__ out)
{
  __shared__ __attribute__((aligned(16))) u16 h0f[2][16*HST];   // 16.9KB
  __shared__ __attribute__((aligned(16))) u16 h1f[3][16*HST];   // 25.3KB (ring)
  __shared__ __attribute__((aligned(16))) u16 lat_s[16*136];    // 4.3KB

  const u16* __restrict__ w_lh  = ws + OFF_LH;
  const u16* __restrict__ w_lc  = ws + OFF_LC;
  const u16* __restrict__ w_ih0 = ws + OFF_IH0;
  const u16* __restrict__ w_hh0 = ws + OFF_HH0;
  const u16* __restrict__ w_ih1 = ws + OFF_IH1;
  const u16* __restrict__ w_hh1 = ws + OFF_HH1;
  const u16* __restrict__ w_out = ws + OFF_OUT;

  const int tid  = threadIdx.x;
  const int w    = tid >> 6;          // wave 0..7
  const int lane = tid & 63;
  const int col  = lane & 15;
  const int quad = lane >> 4;
  const int bid  = blockIdx.x;        // 0..255
  const int s    = bid & 3;           // column slice (64 cols)
  const int g    = bid >> 2;          // batch group (16 rows), 0..63
  const int hct4 = w & 3;             // 16-col subtile within slice
  const int hrow = quad * 4;
  const int l8   = lane * 8;
  const int ctb  = s*64 + hct4*16;    // global h-col base of wave's tile
  const u32 voffW = (u32)((s*4 + hct4) * 8192 + lane * 16);
  const int hreadR = col * HST + quad * 8;   // A-frag read (16 rows)
  char* cm = (char*)comm;

  // ---- stage latent (bf16), 16 rows ----
  for (int i = tid; i < 16*128; i += 512){
    int b = i >> 7, k = i & 127;
    lat_s[b*136 + k] = f2bf(latent[(g*16 + b)*128 + k]);
  }
  __syncthreads();

  // ---- prologue: h(-1) full (local): 32 tile-tasks, 4 per wave ----
  #pragma unroll 1
  for (int i = 0; i < 4; ++i){
    int task = w*4 + i;
    int layer = task >> 4, ct = task & 15;
    int nt = layer*16 + ct;
    float bias = b_lh[nt*16 + col];
    f32x4 a = {bias, bias, bias, bias};
    #pragma unroll
    for (int kt = 0; kt < 4; ++kt){
      bf16x8 la = ld8(&lat_s[col*136 + kt*32 + quad*8]);
      a = mfma16(la, ld8(w_lh + ((nt*4 + kt) << 9) + l8), a);
    }
    u16* dst = layer ? h1f[2] : h0f[1];   // h1(-1) -> ring slot 2
    #pragma unroll
    for (int rr = 0; rr < 4; ++rr)
      dst[(hrow + rr)*HST + ct*16 + col] = f2bf(a[rr]);
  }

  bf16x8 latA[4];
  #pragma unroll
  for (int kt = 0; kt < 4; ++kt)
    latA[kt] = ld8(&lat_s[col*136 + kt*32 + quad*8]);

  f32x4 gx0[4] = {};
  float bias1[4] = {};
  float c0[4] = {}, c1[4] = {};
  const float bo = (w == 0) ? b_out[s*16 + col] : 0.f;

  if (w < 4){
    { float bias = b_lc[ctb + col]; f32x4 a = {bias,bias,bias,bias};
      int nt0 = s*4 + hct4;
      #pragma unroll
      for (int kt = 0; kt < 4; ++kt)
        a = mfma16(latA[kt], ld8(w_lc + ((nt0*4 + kt) << 9) + l8), a);
      #pragma unroll
      for (int rr = 0; rr < 4; ++rr) c0[rr] = a[rr]; }
    #pragma unroll
    for (int g_ = 0; g_ < 4; ++g_){
      int nt = g_*16 + s*4 + hct4;
      float bias = b_ih0[nt*16 + col] + b_hh0[nt*16 + col];
      f32x4 a = {bias, bias, bias, bias};
      #pragma unroll
      for (int kt = 0; kt < 4; ++kt)
        a = mfma16(latA[kt], ld8(w_ih0 + ((nt*4 + kt) << 9) + l8), a);
      gx0[g_] = a;
    }
  } else {
    { float bias = b_lc[256 + ctb + col]; f32x4 a = {bias,bias,bias,bias};
      int nt1 = 16 + s*4 + hct4;
      #pragma unroll
      for (int kt = 0; kt < 4; ++kt)
        a = mfma16(latA[kt], ld8(w_lc + ((nt1*4 + kt) << 9) + l8), a);
      #pragma unroll
      for (int rr = 0; rr < 4; ++rr) c1[rr] = a[rr]; }
    #pragma unroll
    for (int g_ = 0; g_ < 4; ++g_){
      int nt = g_*16 + s*4 + hct4;
      bias1[g_] = b_ih1[nt*16 + col] + b_hh1[nt*16 + col];
    }
  }

  // partner/payload/flag addressing (partner bid = g*4 + ps; 3 partners)
  const int wl = w & 3;
  const int havep = (wl < 3);
  int ps = (wl < s) ? wl : wl + 1;          // {0..3}\{s} for wl=0..2
  if (!havep) ps = 0;
  const int kindm = (w < 4) ? 0 : 1;
  const char* ppay = cm + OBOX(g*4 + ps, kindm, 0) + lane*32;
  const char* fq   = cm + FLAGQ(g*4 + ps, kindm);
  u32* fmyw = (u32*)(cm + FLAGQ(bid, kindm)) + wl;
  char* pub_own = cm + OBOX(bid, kindm, 0) + hct4*512 + lane*8;
  int dead = 0;
  u32x4 fpre = {0,0,0,0};   // prefetched partner flag quad

  __syncthreads();

  // ---- prologue X': gates(0) -> nonlin -> h0(0) own + pub + flag (w0-3) ----
  bf16x8 Pq0[4], Pq1[4], Pq2[4], Pq3[4];
  f32x4 acc0, acc1, acc2, acc3;
  bf16x8 a0;
  if (w < 4){
    ISSUE4(Pq0, w_hh0, 0); ISSUE4(Pq1, w_hh0, 1);
    ISSUE4(Pq2, w_hh0, 2); ISSUE4(Pq3, w_hh0, 3);
    const u16* h0m1 = h0f[1];
    acc0 = gx0[0]; acc1 = gx0[1]; acc2 = gx0[2]; acc3 = gx0[3];
    WAITC(Pq0);      a0 = ld8(&h0m1[hreadR + 0*32]); MFMA4(a0, Pq0); ISSUE4(Pq0, w_hh0, 4);
    WAITC(Pq1);      a0 = ld8(&h0m1[hreadR + 1*32]); MFMA4(a0, Pq1); ISSUE4(Pq1, w_hh0, 5);
    WAITC(Pq2);      a0 = ld8(&h0m1[hreadR + 2*32]); MFMA4(a0, Pq2); ISSUE4(Pq2, w_hh0, 6);
    WAITC(Pq3);      a0 = ld8(&h0m1[hreadR + 3*32]); MFMA4(a0, Pq3); ISSUE4(Pq3, w_hh0, 7);
    WAITC(Pq0);      a0 = ld8(&h0m1[hreadR + 4*32]); MFMA4(a0, Pq0);
    WAITN(Pq1, "8"); a0 = ld8(&h0m1[hreadR + 5*32]); MFMA4(a0, Pq1);
    WAITN(Pq2, "4"); a0 = ld8(&h0m1[hreadR + 6*32]); MFMA4(a0, Pq2);
    WAITN(Pq3, "0"); a0 = ld8(&h0m1[hreadR + 7*32]); MFMA4(a0, Pq3);
    u32 plo = 0, phi = 0;
    #pragma unroll
    for (int rr = 0; rr < 4; ++rr){
      float ii = sigm(acc0[rr]);
      float ff = sigm(acc1[rr]);
      float gg = tanh_f(acc2[rr]);
      float oo = sigm(acc3[rr]);
      float c = ff*c0[rr] + ii*gg;
      c0[rr] = c;
      u16 hb = f2bf(oo * tanh_f(c));
      h0f[0][(hrow + rr)*HST + ctb + col] = hb;   // h0(0), slot 0
      if (rr & 2) phi |= (u32)hb << ((rr & 1)*16);
      else        plo |= (u32)hb << ((rr & 1)*16);
    }
    pub8(pub_own, plo, phi);                       // pub slot 0
    VDRAIN();
    __builtin_amdgcn_sched_barrier(0);
    if (lane == 0) stflag(fmyw, 1u);
    if (havep)
      asm volatile("global_load_dwordx4 %0, %1, off sc0 sc1"
        : "=&v"(fpre) : "v"(fq) : "memory");
    // NO trailing reissue: next chunks issued in G(0)
  }
  // crew1: no prologue issues; its first chunks are issued in G(0)

  int m0 = 0, m1 = 2, m2 = 1;   // h1 ring: h1(t)=m0, h1(t-1)=m1, h1(t-2)=m2

  for (int t = 0; t < 256; ++t){
    const int p = t & 1;
    u16* h0c  = h0f[p];        // h0(t)
    u16* h0n  = h0f[p ^ 1];    // h0(t+1) target
    u16* h1c  = h1f[m0];       // h1(t) target
    u16* h1pr = h1f[m1];       // h1(t-1)

    // ======== phase G: poll(clean) -> payload -> weight-issue -> wait(16) ========
    if (w < 4){
      if (havep){
        asm volatile("s_waitcnt vmcnt(0)" : "+v"(fpre) :: "memory");
        u32 tgt = (u32)(t+1);
        if (!dead && !(fpre[0] >= tgt && fpre[1] >= tgt && fpre[2] >= tgt && fpre[3] >= tgt)){
          int gc = 0;
          for(;;){
            u32x4 fa;
            asm volatile(
              "global_load_dwordx4 %0, %1, off sc0 sc1\n\ts_waitcnt vmcnt(0)"
              : "=&v"(fa) : "v"(fq) : "memory");
            if (fa[0] >= tgt && fa[1] >= tgt && fa[2] >= tgt && fa[3] >= tgt) break;
            if (++gc > SPIN_LIMIT){ dead = 1; break; }
          }
        }
        const char* pp = ppay + (p << 11);
        u32x4 q0, q1;
        asm volatile(
          "global_load_dwordx4 %0, %2, off sc0 sc1\n\t"
          "global_load_dwordx4 %1, %3, off sc0 sc1"
          : "=&v"(q0), "=&v"(q1) : "v"(pp), "v"(pp+16) : "memory");
        ISSUE4(Pq0, w_hh0, 0); ISSUE4(Pq1, w_hh0, 1);
        ISSUE4(Pq2, w_hh0, 2); ISSUE4(Pq3, w_hh0, 3);
        asm volatile("s_waitcnt vmcnt(16)" : "+v"(q0), "+v"(q1) :: "memory");
        scat8(h0c, q0, q1, ps, lane);
      } else {
        ISSUE4(Pq0, w_hh0, 0); ISSUE4(Pq1, w_hh0, 1);
        ISSUE4(Pq2, w_hh0, 2); ISSUE4(Pq3, w_hh0, 3);
      }
    } else {
      if (t > 0 && havep){
        asm volatile("s_waitcnt vmcnt(0)" : "+v"(fpre) :: "memory");
        u32 tgt = (u32)t;
        if (!dead && !(fpre[0] >= tgt && fpre[1] >= tgt && fpre[2] >= tgt && fpre[3] >= tgt)){
          int gc = 0;
          for(;;){
            u32x4 fa;
            asm volatile(
              "global_load_dwordx4 %0, %1, off sc0 sc1\n\ts_waitcnt vmcnt(0)"
              : "=&v"(fa) : "v"(fq) : "memory");
            if (fa[0] >= tgt && fa[1] >= tgt && fa[2] >= tgt && fa[3] >= tgt) break;
            if (++gc > SPIN_LIMIT){ dead = 1; break; }
          }
        }
        const char* pp = ppay + ((p^1) << 11);
        u32x4 q0, q1;
        asm volatile(
          "global_load_dwordx4 %0, %2, off sc0 sc1\n\t"
          "global_load_dwordx4 %1, %3, off sc0 sc1"
          : "=&v"(q0), "=&v"(q1) : "v"(pp), "v"(pp+16) : "memory");
        ISSUE4(Pq0, w_hh1, 0); ISSUE4(Pq1, w_hh1, 1);
        ISSUE4(Pq2, w_hh1, 2); ISSUE4(Pq3, w_hh1, 3);
        asm volatile("s_waitcnt vmcnt(16)" : "+v"(q0), "+v"(q1) :: "memory");
        scat8(h1pr, q0, q1, ps, lane);
      } else {
        ISSUE4(Pq0, w_hh1, 0); ISSUE4(Pq1, w_hh1, 1);
        ISSUE4(Pq2, w_hh1, 2); ISSUE4(Pq3, w_hh1, 3);
      }
    }
    BARX();   // bar1: h0(t) and h1(t-1) full in LDS; weights in flight

    // ======== phase X ========
    if (w < 4){
      // gates(t+1) = gx0 + w_hh0*h0(t) -> nonlin -> h0(t+1) own + pub
      acc0 = gx0[0]; acc1 = gx0[1]; acc2 = gx0[2]; acc3 = gx0[3];
      WAITC(Pq0);      a0 = ld8(&h0c[hreadR + 0*32]); MFMA4(a0, Pq0); ISSUE4(Pq0, w_hh0, 4);
      WAITC(Pq1);      a0 = ld8(&h0c[hreadR + 1*32]); MFMA4(a0, Pq1); ISSUE4(Pq1, w_hh0, 5);
      WAITC(Pq2);      a0 = ld8(&h0c[hreadR + 2*32]); MFMA4(a0, Pq2); ISSUE4(Pq2, w_hh0, 6);
      WAITC(Pq3);      a0 = ld8(&h0c[hreadR + 3*32]); MFMA4(a0, Pq3); ISSUE4(Pq3, w_hh0, 7);
      WAITC(Pq0);      a0 = ld8(&h0c[hreadR + 4*32]); MFMA4(a0, Pq0);
      WAITN(Pq1, "8"); a0 = ld8(&h0c[hreadR + 5*32]); MFMA4(a0, Pq1);
      WAITN(Pq2, "4"); a0 = ld8(&h0c[hreadR + 6*32]); MFMA4(a0, Pq2);
      WAITN(Pq3, "0"); a0 = ld8(&h0c[hreadR + 7*32]); MFMA4(a0, Pq3);
      u32 plo = 0, phi = 0;
      #pragma unroll
      for (int rr = 0; rr < 4; ++rr){
        float ii = sigm(acc0[rr]);
        float ff = sigm(acc1[rr]);
        float gg = tanh_f(acc2[rr]);
        float oo = sigm(acc3[rr]);
        float c = ff*c0[rr] + ii*gg;
        c0[rr] = c;
        u16 hb = f2bf(oo * tanh_f(c));
        h0n[(hrow + rr)*HST + ctb + col] = hb;     // h0(t+1)
        if (rr & 2) phi |= (u32)hb << ((rr & 1)*16);
        else        plo |= (u32)hb << ((rr & 1)*16);
      }
      pub8(pub_own + ((p^1) << 11), plo, phi);
      VDRAIN();  // 1 pub store (queue otherwise empty)
      __builtin_amdgcn_sched_barrier(0);
      if (lane == 0) stflag(fmyw, (u32)(t+2));
      if (havep)
        asm volatile("global_load_dwordx4 %0, %1, off sc0 sc1"
          : "=&v"(fpre) : "v"(fq) : "memory");
      if (w == 0 && t >= 2){
        // out-proj(t-2): tile s; h1f[m2] untouched this phase; queue ~empty
        const u16* h1o = h1f[m2];
        f32x4 o = {bo, bo, bo, bo};
        #pragma unroll
        for (int kt = 0; kt < 8; ++kt){
          bf16x8 af = ld8(&h1o[hreadR + kt*32]);
          o = mfma16(af, ld8(w_out + ((s*8 + kt) << 9) + l8), o);
        }
        #pragma unroll
        for (int rr = 0; rr < 4; ++rr){
          int b = g*16 + hrow + rr;
          __builtin_nontemporal_store(o[rr], &out[(b*256 + (t-2))*64 + s*16 + col]);
        }
      }
    } else {
      // bias1 + w_hh1*h1(t-1) + w_ih1*h0(t), 16-chunk streamed rotation
      acc0 = (f32x4){bias1[0],bias1[0],bias1[0],bias1[0]};
      acc1 = (f32x4){bias1[1],bias1[1],bias1[1],bias1[1]};
      acc2 = (f32x4){bias1[2],bias1[2],bias1[2],bias1[2]};
      acc3 = (f32x4){bias1[3],bias1[3],bias1[3],bias1[3]};
      WAITC(Pq0);      a0 = ld8(&h1pr[hreadR + 0*32]); MFMA4(a0, Pq0); ISSUE4(Pq0, w_hh1, 4);
      WAITC(Pq1);      a0 = ld8(&h1pr[hreadR + 1*32]); MFMA4(a0, Pq1); ISSUE4(Pq1, w_hh1, 5);
      WAITC(Pq2);      a0 = ld8(&h1pr[hreadR + 2*32]); MFMA4(a0, Pq2); ISSUE4(Pq2, w_hh1, 6);
      WAITC(Pq3);      a0 = ld8(&h1pr[hreadR + 3*32]); MFMA4(a0, Pq3); ISSUE4(Pq3, w_hh1, 7);
      WAITC(Pq0);      a0 = ld8(&h1pr[hreadR + 4*32]); MFMA4(a0, Pq0); ISSUE4(Pq0, w_ih1, 0);
      WAITC(Pq1);      a0 = ld8(&h1pr[hreadR + 5*32]); MFMA4(a0, Pq1); ISSUE4(Pq1, w_ih1, 1);
      WAITC(Pq2);      a0 = ld8(&h1pr[hreadR + 6*32]); MFMA4(a0, Pq2); ISSUE4(Pq2, w_ih1, 2);
      WAITC(Pq3);      a0 = ld8(&h1pr[hreadR + 7*32]); MFMA4(a0, Pq3); ISSUE4(Pq3, w_ih1, 3);
      WAITC(Pq0);      a0 = ld8(&h0c[hreadR + 0*32]); MFMA4(a0, Pq0); ISSUE4(Pq0, w_ih1, 4);
      WAITC(Pq1);      a0 = ld8(&h0c[hreadR + 1*32]); MFMA4(a0, Pq1); ISSUE4(Pq1, w_ih1, 5);
      WAITC(Pq2);      a0 = ld8(&h0c[hreadR + 2*32]); MFMA4(a0, Pq2); ISSUE4(Pq2, w_ih1, 6);
      WAITC(Pq3);      a0 = ld8(&h0c[hreadR + 3*32]); MFMA4(a0, Pq3); ISSUE4(Pq3, w_ih1, 7);
      WAITC(Pq0);      a0 = ld8(&h0c[hreadR + 4*32]); MFMA4(a0, Pq0);
      WAITN(Pq1, "8"); a0 = ld8(&h0c[hreadR + 5*32]); MFMA4(a0, Pq1);
      WAITN(Pq2, "4"); a0 = ld8(&h0c[hreadR + 6*32]); MFMA4(a0, Pq2);
      WAITN(Pq3, "0"); a0 = ld8(&h0c[hreadR + 7*32]); MFMA4(a0, Pq3);
      u32 plo = 0, phi = 0;
      #pragma unroll
      for (int rr = 0; rr < 4; ++rr){
        float ii = sigm(acc0[rr]);
        float ff = sigm(acc1[rr]);
        float gg = tanh_f(acc2[rr]);
        float oo = sigm(acc3[rr]);
        float c = ff*c1[rr] + ii*gg;
        c1[rr] = c;
        u16 hb = f2bf(oo * tanh_f(c));
        h1c[(hrow + rr)*HST + ctb + col] = hb;     // h1(t)
        if (rr & 2) phi |= (u32)hb << ((rr & 1)*16);
        else        plo |= (u32)hb << ((rr & 1)*16);
      }
      pub8(pub_own + (p << 11), plo, phi);
      VDRAIN();  // 1 pub store
      __builtin_amdgcn_sched_barrier(0);
      if (lane == 0) stflag(fmyw, (u32)(t+1));
      if (havep)
        asm volatile("global_load_dwordx4 %0, %1, off sc0 sc1"
          : "=&v"(fpre) : "v"(fq) : "memory");
    }
    BARX();   // bar2: h0(t+1) own + h1(t) own tiles in LDS

    int tm = m2; m2 = m1; m1 = m0; m0 = tm;   // rotate h1 ring
  }

  // ---- epilogue: gather h1(255) into slot 0; out(254) from slot 2; out(255) ----
  if (w >= 4){
    if (havep)
      gatherF1(h1f[0], ppay + (1 << 11), fq, ps, lane, 256u, &dead);
  } else if (w == 0){
    const u16* h1o = h1f[2];   // h1(254)
    f32x4 o = {bo, bo, bo, bo};
    #pragma unroll
    for (int kt = 0; kt < 8; ++kt){
      bf16x8 af = ld8(&h1o[hreadR + kt*32]);
      o = mfma16(af, ld8(w_out + ((s*8 + kt) << 9) + l8), o);
    }
    #pragma unroll
    for (int rr = 0; rr < 4; ++rr){
      int b = g*16 + hrow + rr;
      __builtin_nontemporal_store(o[rr], &out[(b*256 + 254)*64 + s*16 + col]);
    }
  }
  BARX();
  if (w == 0){
    const u16* h1fin = h1f[0];  // h1(255)
    f32x4 o = {bo, bo, bo, bo};
    #pragma unroll
    for (int kt = 0; kt < 8; ++kt){
      bf16x8 af = ld8(&h1fin[hreadR + kt*32]);
      o = mfma16(af, ld8(w_out + ((s*8 + kt) << 9) + l8), o);
    }
    #pragma unroll
    for (int rr = 0; rr < 4; ++rr){
      int b = g*16 + hrow + rr;
      __builtin_nontemporal_store(o[rr], &out[(b*256 + 255)*64 + s*16 + col]);
    }
  }
}

extern "C" void kernel_launch(void* const* d_in, const int* in_sizes, int n_in,
                              void* d_out, int out_size, void* d_ws, size_t ws_size,
                              hipStream_t stream)
{
  (void)in_sizes; (void)n_in; (void)out_size; (void)ws_size;
  const float* latent = (const float*)d_in[0];
  const float* w_lh   = (const float*)d_in[1];
  const float* b_lh   = (const float*)d_in[2];
  const float* w_lc   = (const float*)d_in[3];
  const float* b_lc   = (const float*)d_in[4];
  const float* w_ih0  = (const float*)d_in[5];
  const float* w_hh0  = (const float*)d_in[6];
  const float* b_ih0  = (const float*)d_in[7];
  const float* b_hh0  = (const float*)d_in[8];
  const float* w_ih1  = (const float*)d_in[9];
  const float* w_hh1  = (const float*)d_in[10];
  const float* b_ih1  = (const float*)d_in[11];
  const float* b_hh1  = (const float*)d_in[12];
  const float* w_out  = (const float*)d_in[13];
  const float* b_out  = (const float*)d_in[14];
  u16* ws = (u16*)d_ws;
  float* out = (float*)d_out;

  auto cvt = [&](const float* src, int off, int ntiles, int kbshift){
    int n = ntiles << (kbshift + 9);
    convert_swizzle<<<dim3((n + 255)/256), dim3(256), 0, stream>>>(src, ws + off, ntiles, kbshift);
  };
  cvt(w_lh,  OFF_LH,  32, 2);
  cvt(w_lc,  OFF_LC,  32, 2);
  cvt(w_ih0, OFF_IH0, 64, 2);
  cvt(w_hh0, OFF_HH0, 64, 3);
  cvt(w_ih1, OFF_IH1, 64, 3);
  cvt(w_hh1, OFF_HH1, 64, 3);
  cvt(w_out, OFF_OUT, 4, 3);

  // reset per-wave flag quads (captured graph node; monotonic from 0 each replay)
  hipMemsetAsync((char*)d_ws + FLAG_B, 0, 256*2*16, stream);

  lstm_fused<<<dim3(256), dim3(512), 0, stream>>>(latent, b_lh, b_lc, b_ih0, b_hh0,
                                                  b_ih1, b_hh1, b_out, ws, ws, out);
}

// Round 11
// 1332.183 us; speedup vs baseline: 1.4076x; 1.4076x over previous
//
#include <hip/hip_runtime.h>

// LSTMDecoder: B=1024, L=128, H=256, OUT=64, T=256, 2 layers.
// R21: weight-STATIONARY recurrent matrices in VGPRs. R20 regressed
// (1454->1880): moving weight issue into G cost cold-start latency at X;
// real bottleneck is the ~6k cyc/step L1-return-path time of the 384KB/CU
// weight stream (R18/R19 flat despite halved exchange confirms co-bound).
// R21 removes the bytes: at 1 block/CU, 512 thr (2 waves/SIMD -> 256 VGPR
// budget), each wave holds its recurrent tile (4 gates x 16 cols x K=256 =
// 32 bf16x8 = 128 VGPR) in ONE shared array Wst[32]: crew0 loads hh0,
// crew1 loads hh1 (divergent load, same registers -> no double cost).
// hh0/hh1 matmuls become pure register MFMA; only ih1 (128KB/CU) streams,
// depth-2 Pq (32 VGPR): chunks 0,1 issued in G (after poll, payload wait
// vmcnt(8)), consumed mid-X AFTER the 8 hh1 register chunks (~400cyc
// cover -> no R20 cold start), rotation vmcnt(4)...(0) ends X clean.
// crew0 has NO vmem in X except its 8B pub -> VDRAIN = 1 store; its G
// polls a clean queue. No fpre. Est VGPR ~210 (R12 spill rule: asm Pq
// regs must never spill; margin kept). Partition/protocol/slots/flags =
// R19 verbatim (proven): 64x4, 2-phase {G,bar,X,bar}, per-wave flags
// posted pre-barrier, 2-slot boxes, 8B pubs, 3-deep h1 ring, spin-guard.

typedef float f32x4 __attribute__((ext_vector_type(4)));
typedef short bf16x8 __attribute__((ext_vector_type(8)));
typedef unsigned short u16;
typedef unsigned int u32;
typedef unsigned int u32x2 __attribute__((ext_vector_type(2)));
typedef unsigned int u32x4 __attribute__((ext_vector_type(4)));

#define OFF_LH   0          // 32 tiles, KB=4
#define OFF_LC   65536      // 32 tiles, KB=4
#define OFF_IH0  131072     // 64 tiles, KB=4
#define OFF_HH0  262144     // 64 tiles, KB=8
#define OFF_IH1  524288     // 64 tiles, KB=8
#define OFF_HH1  786432     // 64 tiles, KB=8
#define OFF_OUT  1048576    // 4 tiles,  KB=8

// payload boxes: 2KB x 256 blocks x 2 kinds x 2 slots = 2MB
#define COMM_B   2228224
#define OBOX(bid,kind,slot) (COMM_B + ((((bid)*2+(kind))*2+(slot)) << 11))
// per-wave flag quads: 16B per (bid,kind)
#define FLAG_B   (COMM_B + 2097152)
#define FLAGQ(bid,kind) (FLAG_B + (((bid)*2+(kind)) << 4))
#define SPIN_LIMIT (1<<15)
#define HST 264

__device__ __forceinline__ u16 f2bf(float x){
  unsigned u = __builtin_bit_cast(unsigned, x);
  return (u16)((u + 0x7fffu + ((u >> 16) & 1u)) >> 16);  // RNE
}

__global__ __launch_bounds__(256) void convert_swizzle(
    const float* __restrict__ src, u16* __restrict__ dst,
    int ntiles, int kbshift)
{
  int idx = blockIdx.x * 256 + threadIdx.x;
  int kblocks = 1 << kbshift;
  int n = ntiles << (kbshift + 9);
  if (idx >= n) return;
  int j    = idx & 7;
  int lane = (idx >> 3) & 63;
  int t3   = idx >> 9;
  int kt   = t3 & (kblocks - 1);
  int nt   = t3 >> kbshift;
  int row  = nt * 16 + (lane & 15);
  int k    = kt * 32 + (lane >> 4) * 8 + j;
  dst[idx] = f2bf(src[row * (kblocks * 32) + k]);
}

__device__ __forceinline__ f32x4 mfma16(bf16x8 a, bf16x8 b, f32x4 c){
  return __builtin_amdgcn_mfma_f32_16x16x32_bf16(a, b, c, 0, 0, 0);
}
__device__ __forceinline__ bf16x8 ld8(const u16* p){ return *(const bf16x8*)p; }
__device__ __forceinline__ float sigm(float x){ return 1.f/(1.f + __expf(-x)); }
__device__ __forceinline__ float tanh_f(float x){ return 1.f - 2.f/(__expf(2.f*x) + 1.f); }

#define ISSUE4(Q, seg, kt) \
  asm volatile( \
    "global_load_dwordx4 %0, %4, %8\n\t" \
    "global_load_dwordx4 %1, %5, %8\n\t" \
    "global_load_dwordx4 %2, %6, %8\n\t" \
    "global_load_dwordx4 %3, %7, %8" \
    : "=&v"(Q[0]), "=&v"(Q[1]), "=&v"(Q[2]), "=&v"(Q[3]) \
    : "v"(voffW +           (u32)((kt)*1024)), \
      "v"(voffW + 131072u + (u32)((kt)*1024)), \
      "v"(voffW + 262144u + (u32)((kt)*1024)), \
      "v"(voffW + 393216u + (u32)((kt)*1024)), \
      "s"(seg) \
    : "memory")

#define WAITN(Q, lit) \
  asm volatile("s_waitcnt vmcnt(" lit ")" \
    : "+v"(Q[0]), "+v"(Q[1]), "+v"(Q[2]), "+v"(Q[3]) :: "memory")

#define MFMA4(afrag, Q) { \
  acc0 = mfma16(afrag, Q[0], acc0); \
  acc1 = mfma16(afrag, Q[1], acc1); \
  acc2 = mfma16(afrag, Q[2], acc2); \
  acc3 = mfma16(afrag, Q[3], acc3); }

// 4 MFMAs against the stationary register tile, K-chunk kt (constant!)
#define MFMA4W(afrag, kt) { \
  acc0 = mfma16(afrag, Wst[0*8+(kt)], acc0); \
  acc1 = mfma16(afrag, Wst[1*8+(kt)], acc1); \
  acc2 = mfma16(afrag, Wst[2*8+(kt)], acc2); \
  acc3 = mfma16(afrag, Wst[3*8+(kt)], acc3); }

#define BARX() asm volatile("s_waitcnt lgkmcnt(0)\n\ts_barrier" ::: "memory")
#define VDRAIN() asm volatile("s_waitcnt vmcnt(0)" ::: "memory")

__device__ __forceinline__ void stflag(u32* p, u32 v){
  __hip_atomic_store(p, v, __ATOMIC_RELAXED, __HIP_MEMORY_SCOPE_AGENT);
}
// coalesced 8B record: {rows hrow+0,+1 | rows hrow+2,+3} for one col
__device__ __forceinline__ void pub8(char* p, u32 lo, u32 hi){
  u32x2 v = {lo, hi};
  asm volatile("global_store_dwordx2 %0, %1, off sc0 sc1" :: "v"(p), "v"(v) : "memory");
}

// scatter one partner box's 32B/lane of col-records into full-h LDS
__device__ __forceinline__ void scat8(u16* hdst, u32x4 q0, u32x4 q1, int ps, int lane){
  const int r  = lane >> 4;            // producer wave region (hct4)
  const int cb = ps*64 + r*16;         // col base in full-h LDS
  #pragma unroll
  for (int j = 0; j < 4; ++j){
    u32 lo = (j < 2) ? q0[2*j]   : q1[2*(j-2)];
    u32 hi = (j < 2) ? q0[2*j+1] : q1[2*(j-2)+1];
    int pl = (lane & 15)*4 + j;        // producer lane within region
    u16* dst = &hdst[((pl >> 4)*4)*HST + cb + (pl & 15)];
    dst[0]     = (u16)lo;
    dst[HST]   = (u16)(lo >> 16);
    dst[2*HST] = (u16)hi;
    dst[3*HST] = (u16)(hi >> 16);
  }
}

// clean-queue gather: poll flags + payload + scatter
__device__ __forceinline__ void gatherF1(u16* hdst,
    const char* pay, const char* fq, int ps, int lane, u32 tgt, int* dead)
{
  if (!*dead){
    int gc = 0;
    for(;;){
      u32x4 fa;
      asm volatile(
        "global_load_dwordx4 %0, %1, off sc0 sc1\n\ts_waitcnt vmcnt(0)"
        : "=&v"(fa) : "v"(fq) : "memory");
      if (fa[0] >= tgt && fa[1] >= tgt && fa[2] >= tgt && fa[3] >= tgt) break;
      if (++gc > SPIN_LIMIT){ *dead = 1; break; }
    }
  }
  u32x4 q0, q1;
  asm volatile(
    "global_load_dwordx4 %0, %2, off sc0 sc1\n\t"
    "global_load_dwordx4 %1, %3, off sc0 sc1"
    : "=&v"(q0), "=&v"(q1)
    : "v"(pay), "v"(pay+16)
    : "memory");
  asm volatile("s_waitcnt vmcnt(0)" : "+v"(q0), "+v"(q1) :: "memory");
  scat8(hdst, q0, q1, ps, lane);
}

__global__ __launch_bounds__(512)
void lstm_fused(
    const float* __restrict__ latent,
    const float* __restrict__ b_lh, const float* __restrict__ b_lc,
    const float* __restrict__ b_ih0, const float* __restrict__ b_hh0,
    const float* __restrict__ b_ih1, const float* __restrict__ b_hh1,
    const float* __restrict__ b_out,
    const u16* __restrict__ ws,
    u16* __restrict__ comm,
    float* __restrict__ out)
{
  __shared__ __attribute__((aligned(16))) u16 h0f[2][16*HST];   // 16.9KB
  __shared__ __attribute__((aligned(16))) u16 h1f[3][16*HST];   // 25.3KB (ring)
  __shared__ __attribute__((aligned(16))) u16 lat_s[16*136];    // 4.3KB

  const u16* __restrict__ w_lh  = ws + OFF_LH;
  const u16* __restrict__ w_lc  = ws + OFF_LC;
  const u16* __restrict__ w_ih0 = ws + OFF_IH0;
  const u16* __restrict__ w_hh0 = ws + OFF_HH0;
  const u16* __restrict__ w_ih1 = ws + OFF_IH1;
  const u16* __restrict__ w_hh1 = ws + OFF_HH1;
  const u16* __restrict__ w_out = ws + OFF_OUT;

  const int tid  = threadIdx.x;
  const int w    = tid >> 6;          // wave 0..7
  const int lane = tid & 63;
  const int col  = lane & 15;
  const int quad = lane >> 4;
  const int bid  = blockIdx.x;        // 0..255
  const int s    = bid & 3;           // column slice (64 cols)
  const int g    = bid >> 2;          // batch group (16 rows), 0..63
  const int hct4 = w & 3;             // 16-col subtile within slice
  const int hrow = quad * 4;
  const int l8   = lane * 8;
  const int ctb  = s*64 + hct4*16;    // global h-col base of wave's tile
  const u32 voffW = (u32)((s*4 + hct4) * 8192 + lane * 16);
  const int hreadR = col * HST + quad * 8;   // A-frag read (16 rows)
  char* cm = (char*)comm;

  // ---- stage latent (bf16), 16 rows ----
  for (int i = tid; i < 16*128; i += 512){
    int b = i >> 7, k = i & 127;
    lat_s[b*136 + k] = f2bf(latent[(g*16 + b)*128 + k]);
  }
  __syncthreads();

  // ---- stationary recurrent tile: crew0 = hh0 slice, crew1 = hh1 slice ----
  bf16x8 Wst[32];
  {
    const u16* wsrc = (w < 4) ? w_hh0 : w_hh1;
    #pragma unroll
    for (int g_ = 0; g_ < 4; ++g_){
      #pragma unroll
      for (int kt = 0; kt < 8; ++kt){
        int nt = g_*16 + s*4 + hct4;
        Wst[g_*8 + kt] = ld8(wsrc + ((nt*8 + kt) << 9) + l8);
      }
    }
  }

  // ---- prologue: h(-1) full (local): 32 tile-tasks, 4 per wave ----
  #pragma unroll 1
  for (int i = 0; i < 4; ++i){
    int task = w*4 + i;
    int layer = task >> 4, ct = task & 15;
    int nt = layer*16 + ct;
    float bias = b_lh[nt*16 + col];
    f32x4 a = {bias, bias, bias, bias};
    #pragma unroll
    for (int kt = 0; kt < 4; ++kt){
      bf16x8 la = ld8(&lat_s[col*136 + kt*32 + quad*8]);
      a = mfma16(la, ld8(w_lh + ((nt*4 + kt) << 9) + l8), a);
    }
    u16* dst = layer ? h1f[2] : h0f[1];   // h1(-1) -> ring slot 2
    #pragma unroll
    for (int rr = 0; rr < 4; ++rr)
      dst[(hrow + rr)*HST + ct*16 + col] = f2bf(a[rr]);
  }

  bf16x8 latA[4];
  #pragma unroll
  for (int kt = 0; kt < 4; ++kt)
    latA[kt] = ld8(&lat_s[col*136 + kt*32 + quad*8]);

  f32x4 gx0[4] = {};
  float bias1[4] = {};
  float c0[4] = {}, c1[4] = {};
  const float bo = (w == 0) ? b_out[s*16 + col] : 0.f;

  if (w < 4){
    { float bias = b_lc[ctb + col]; f32x4 a = {bias,bias,bias,bias};
      int nt0 = s*4 + hct4;
      #pragma unroll
      for (int kt = 0; kt < 4; ++kt)
        a = mfma16(latA[kt], ld8(w_lc + ((nt0*4 + kt) << 9) + l8), a);
      #pragma unroll
      for (int rr = 0; rr < 4; ++rr) c0[rr] = a[rr]; }
    #pragma unroll
    for (int g_ = 0; g_ < 4; ++g_){
      int nt = g_*16 + s*4 + hct4;
      float bias = b_ih0[nt*16 + col] + b_hh0[nt*16 + col];
      f32x4 a = {bias, bias, bias, bias};
      #pragma unroll
      for (int kt = 0; kt < 4; ++kt)
        a = mfma16(latA[kt], ld8(w_ih0 + ((nt*4 + kt) << 9) + l8), a);
      gx0[g_] = a;
    }
  } else {
    { float bias = b_lc[256 + ctb + col]; f32x4 a = {bias,bias,bias,bias};
      int nt1 = 16 + s*4 + hct4;
      #pragma unroll
      for (int kt = 0; kt < 4; ++kt)
        a = mfma16(latA[kt], ld8(w_lc + ((nt1*4 + kt) << 9) + l8), a);
      #pragma unroll
      for (int rr = 0; rr < 4; ++rr) c1[rr] = a[rr]; }
    #pragma unroll
    for (int g_ = 0; g_ < 4; ++g_){
      int nt = g_*16 + s*4 + hct4;
      bias1[g_] = b_ih1[nt*16 + col] + b_hh1[nt*16 + col];
    }
  }

  // partner/payload/flag addressing (partner bid = g*4 + ps; 3 partners)
  const int wl = w & 3;
  const int havep = (wl < 3);
  int ps = (wl < s) ? wl : wl + 1;          // {0..3}\{s} for wl=0..2
  if (!havep) ps = 0;
  const int kindm = (w < 4) ? 0 : 1;
  const char* ppay = cm + OBOX(g*4 + ps, kindm, 0) + lane*32;
  const char* fq   = cm + FLAGQ(g*4 + ps, kindm);
  u32* fmyw = (u32*)(cm + FLAGQ(bid, kindm)) + wl;
  char* pub_own = cm + OBOX(bid, kindm, 0) + hct4*512 + lane*8;
  int dead = 0;

  __syncthreads();

  // ---- prologue X': gates(0) -> nonlin -> h0(0) own + pub + flag (w0-3) ----
  bf16x8 Pq0[4], Pq1[4];       // crew1's depth-2 ih1 pipeline
  f32x4 acc0, acc1, acc2, acc3;
  bf16x8 a0;
  if (w < 4){
    const u16* h0m1 = h0f[1];
    acc0 = gx0[0]; acc1 = gx0[1]; acc2 = gx0[2]; acc3 = gx0[3];
    #pragma unroll
    for (int kt = 0; kt < 8; ++kt){
      a0 = ld8(&h0m1[hreadR + kt*32]);
      MFMA4W(a0, kt);
    }
    u32 plo = 0, phi = 0;
    #pragma unroll
    for (int rr = 0; rr < 4; ++rr){
      float ii = sigm(acc0[rr]);
      float ff = sigm(acc1[rr]);
      float gg = tanh_f(acc2[rr]);
      float oo = sigm(acc3[rr]);
      float c = ff*c0[rr] + ii*gg;
      c0[rr] = c;
      u16 hb = f2bf(oo * tanh_f(c));
      h0f[0][(hrow + rr)*HST + ctb + col] = hb;   // h0(0), slot 0
      if (rr & 2) phi |= (u32)hb << ((rr & 1)*16);
      else        plo |= (u32)hb << ((rr & 1)*16);
    }
    pub8(pub_own, plo, phi);                       // pub slot 0
    VDRAIN();
    __builtin_amdgcn_sched_barrier(0);
    if (lane == 0) stflag(fmyw, 1u);
  }

  int m0 = 0, m1 = 2, m2 = 1;   // h1 ring: h1(t)=m0, h1(t-1)=m1, h1(t-2)=m2

  for (int t = 0; t < 256; ++t){
    const int p = t & 1;
    u16* h0c  = h0f[p];        // h0(t)
    u16* h0n  = h0f[p ^ 1];    // h0(t+1) target
    u16* h1c  = h1f[m0];       // h1(t) target
    u16* h1pr = h1f[m1];       // h1(t-1)

    // ======== phase G ========
    if (w < 4){
      // crew0: clean queue -> pure poll + payload + scatter
      if (havep)
        gatherF1(h0c, ppay + (p << 11), fq, ps, lane, (u32)(t+1), &dead);
    } else {
      if (t > 0 && havep){
        // poll (clean queue)
        if (!dead){
          int gc = 0;
          u32 tgt = (u32)t;
          for(;;){
            u32x4 fa;
            asm volatile(
              "global_load_dwordx4 %0, %1, off sc0 sc1\n\ts_waitcnt vmcnt(0)"
              : "=&v"(fa) : "v"(fq) : "memory");
            if (fa[0] >= tgt && fa[1] >= tgt && fa[2] >= tgt && fa[3] >= tgt) break;
            if (++gc > SPIN_LIMIT){ dead = 1; break; }
          }
        }
        const char* pp = ppay + ((p^1) << 11);
        u32x4 q0, q1;
        asm volatile(
          "global_load_dwordx4 %0, %2, off sc0 sc1\n\t"
          "global_load_dwordx4 %1, %3, off sc0 sc1"
          : "=&v"(q0), "=&v"(q1) : "v"(pp), "v"(pp+16) : "memory");
        ISSUE4(Pq0, w_ih1, 0); ISSUE4(Pq1, w_ih1, 1);   // in flight across bar1
        asm volatile("s_waitcnt vmcnt(8)" : "+v"(q0), "+v"(q1) :: "memory");
        scat8(h1pr, q0, q1, ps, lane);
      } else {
        ISSUE4(Pq0, w_ih1, 0); ISSUE4(Pq1, w_ih1, 1);
      }
    }
    BARX();   // bar1: h0(t) and h1(t-1) full in LDS; ih1 chunks in flight

    // ======== phase X ========
    if (w < 4){
      // gates(t+1) = gx0 + Whh0_reg * h0(t) -> nonlin -> h0(t+1) own + pub
      acc0 = gx0[0]; acc1 = gx0[1]; acc2 = gx0[2]; acc3 = gx0[3];
      #pragma unroll
      for (int kt = 0; kt < 8; ++kt){
        a0 = ld8(&h0c[hreadR + kt*32]);
        MFMA4W(a0, kt);
      }
      u32 plo = 0, phi = 0;
      #pragma unroll
      for (int rr = 0; rr < 4; ++rr){
        float ii = sigm(acc0[rr]);
        float ff = sigm(acc1[rr]);
        float gg = tanh_f(acc2[rr]);
        float oo = sigm(acc3[rr]);
        float c = ff*c0[rr] + ii*gg;
        c0[rr] = c;
        u16 hb = f2bf(oo * tanh_f(c));
        h0n[(hrow + rr)*HST + ctb + col] = hb;     // h0(t+1)
        if (rr & 2) phi |= (u32)hb << ((rr & 1)*16);
        else        plo |= (u32)hb << ((rr & 1)*16);
      }
      pub8(pub_own + ((p^1) << 11), plo, phi);
      VDRAIN();  // 1 pub store (queue otherwise empty)
      __builtin_amdgcn_sched_barrier(0);
      if (lane == 0) stflag(fmyw, (u32)(t+2));
      if (w == 0 && t >= 2){
        // out-proj(t-2): tile s; h1f[m2] untouched this phase
        const u16* h1o = h1f[m2];
        f32x4 o = {bo, bo, bo, bo};
        #pragma unroll
        for (int kt = 0; kt < 8; ++kt){
          bf16x8 af = ld8(&h1o[hreadR + kt*32]);
          o = mfma16(af, ld8(w_out + ((s*8 + kt) << 9) + l8), o);
        }
        #pragma unroll
        for (int rr = 0; rr < 4; ++rr){
          int b = g*16 + hrow + rr;
          __builtin_nontemporal_store(o[rr], &out[(b*256 + (t-2))*64 + s*16 + col]);
        }
      }
    } else {
      // bias1 + Whh1_reg*h1(t-1) (8 register chunks, covers ih1 latency)
      acc0 = (f32x4){bias1[0],bias1[0],bias1[0],bias1[0]};
      acc1 = (f32x4){bias1[1],bias1[1],bias1[1],bias1[1]};
      acc2 = (f32x4){bias1[2],bias1[2],bias1[2],bias1[2]};
      acc3 = (f32x4){bias1[3],bias1[3],bias1[3],bias1[3]};
      #pragma unroll
      for (int kt = 0; kt < 8; ++kt){
        a0 = ld8(&h1pr[hreadR + kt*32]);
        MFMA4W(a0, kt);
      }
      // + w_ih1 * h0(t), depth-2 streamed rotation (chunks 0,1 from G)
      WAITN(Pq0,"4"); a0 = ld8(&h0c[hreadR + 0*32]); MFMA4(a0, Pq0); ISSUE4(Pq0, w_ih1, 2);
      WAITN(Pq1,"4"); a0 = ld8(&h0c[hreadR + 1*32]); MFMA4(a0, Pq1); ISSUE4(Pq1, w_ih1, 3);
      WAITN(Pq0,"4"); a0 = ld8(&h0c[hreadR + 2*32]); MFMA4(a0, Pq0); ISSUE4(Pq0, w_ih1, 4);
      WAITN(Pq1,"4"); a0 = ld8(&h0c[hreadR + 3*32]); MFMA4(a0, Pq1); ISSUE4(Pq1, w_ih1, 5);
      WAITN(Pq0,"4"); a0 = ld8(&h0c[hreadR + 4*32]); MFMA4(a0, Pq0); ISSUE4(Pq0, w_ih1, 6);
      WAITN(Pq1,"4"); a0 = ld8(&h0c[hreadR + 5*32]); MFMA4(a0, Pq1); ISSUE4(Pq1, w_ih1, 7);
      WAITN(Pq0,"4"); a0 = ld8(&h0c[hreadR + 6*32]); MFMA4(a0, Pq0);
      WAITN(Pq1,"0"); a0 = ld8(&h0c[hreadR + 7*32]); MFMA4(a0, Pq1);
      u32 plo = 0, phi = 0;
      #pragma unroll
      for (int rr = 0; rr < 4; ++rr){
        float ii = sigm(acc0[rr]);
        float ff = sigm(acc1[rr]);
        float gg = tanh_f(acc2[rr]);
        float oo = sigm(acc3[rr]);
        float c = ff*c1[rr] + ii*gg;
        c1[rr] = c;
        u16 hb = f2bf(oo * tanh_f(c));
        h1c[(hrow + rr)*HST + ctb + col] = hb;     // h1(t)
        if (rr & 2) phi |= (u32)hb << ((rr & 1)*16);
        else        plo |= (u32)hb << ((rr & 1)*16);
      }
      pub8(pub_own + (p << 11), plo, phi);
      VDRAIN();  // 1 pub store
      __builtin_amdgcn_sched_barrier(0);
      if (lane == 0) stflag(fmyw, (u32)(t+1));
    }
    BARX();   // bar2: h0(t+1) own + h1(t) own tiles in LDS

    int tm = m2; m2 = m1; m1 = m0; m0 = tm;   // rotate h1 ring
  }

  // ---- epilogue: gather h1(255) into slot 0; out(254) from slot 2; out(255) ----
  if (w >= 4){
    if (havep)
      gatherF1(h1f[0], ppay + (1 << 11), fq, ps, lane, 256u, &dead);
  } else if (w == 0){
    const u16* h1o = h1f[2];   // h1(254)
    f32x4 o = {bo, bo, bo, bo};
    #pragma unroll
    for (int kt = 0; kt < 8; ++kt){
      bf16x8 af = ld8(&h1o[hreadR + kt*32]);
      o = mfma16(af, ld8(w_out + ((s*8 + kt) << 9) + l8), o);
    }
    #pragma unroll
    for (int rr = 0; rr < 4; ++rr){
      int b = g*16 + hrow + rr;
      __builtin_nontemporal_store(o[rr], &out[(b*256 + 254)*64 + s*16 + col]);
    }
  }
  BARX();
  if (w == 0){
    const u16* h1fin = h1f[0];  // h1(255)
    f32x4 o = {bo, bo, bo, bo};
    #pragma unroll
    for (int kt = 0; kt < 8; ++kt){
      bf16x8 af = ld8(&h1fin[hreadR + kt*32]);
      o = mfma16(af, ld8(w_out + ((s*8 + kt) << 9) + l8), o);
    }
    #pragma unroll
    for (int rr = 0; rr < 4; ++rr){
      int b = g*16 + hrow + rr;
      __builtin_nontemporal_store(o[rr], &out[(b*256 + 255)*64 + s*16 + col]);
    }
  }
}

extern "C" void kernel_launch(void* const* d_in, const int* in_sizes, int n_in,
                              void* d_out, int out_size, void* d_ws, size_t ws_size,
                              hipStream_t stream)
{
  (void)in_sizes; (void)n_in; (void)out_size; (void)ws_size;
  const float* latent = (const float*)d_in[0];
  const float* w_lh   = (const float*)d_in[1];
  const float* b_lh   = (const float*)d_in[2];
  const float* w_lc   = (const float*)d_in[3];
  const float* b_lc   = (const float*)d_in[4];
  const float* w_ih0  = (const float*)d_in[5];
  const float* w_hh0  = (const float*)d_in[6];
  const float* b_ih0  = (const float*)d_in[7];
  const float* b_hh0  = (const float*)d_in[8];
  const float* w_ih1  = (const float*)d_in[9];
  const float* w_hh1  = (const float*)d_in[10];
  const float* b_ih1  = (const float*)d_in[11];
  const float* b_hh1  = (const float*)d_in[12];
  const float* w_out  = (const float*)d_in[13];
  const float* b_out  = (const float*)d_in[14];
  u16* ws = (u16*)d_ws;
  float* out = (float*)d_out;

  auto cvt = [&](const float* src, int off, int ntiles, int kbshift){
    int n = ntiles << (kbshift + 9);
    convert_swizzle<<<dim3((n + 255)/256), dim3(256), 0, stream>>>(src, ws + off, ntiles, kbshift);
  };
  cvt(w_lh,  OFF_LH,  32, 2);
  cvt(w_lc,  OFF_LC,  32, 2);
  cvt(w_ih0, OFF_IH0, 64, 2);
  cvt(w_hh0, OFF_HH0, 64, 3);
  cvt(w_ih1, OFF_IH1, 64, 3);
  cvt(w_hh1, OFF_HH1, 64, 3);
  cvt(w_out, OFF_OUT, 4, 3);

  // reset per-wave flag quads (captured graph node; monotonic from 0 each replay)
  hipMemsetAsync((char*)d_ws + FLAG_B, 0, 256*2*16, stream);

  lstm_fused<<<dim3(256), dim3(512), 0, stream>>>(latent, b_lh, b_lc, b_ih0, b_hh0,
                                                  b_ih1, b_hh1, b_out, ws, ws, out);
}